// Round 4
// baseline (128.405 us; speedup 1.0000x reference)
//
#include <hip/hip_runtime.h>
#include <hip/hip_bf16.h>

typedef _Float16 half8 __attribute__((ext_vector_type(8)));
typedef _Float16 half4v __attribute__((ext_vector_type(4)));
typedef float floatx4 __attribute__((ext_vector_type(4)));
typedef unsigned int uint4v __attribute__((ext_vector_type(4)));

// 100^(i/8), i=0..7, correctly rounded
__device__ const float FREQS[8] = {
    1.0f, 1.7782794100389228f, 3.1622776601683795f, 5.623413251903491f,
    10.0f, 17.78279410038923f, 31.622776601683793f, 56.23413251903491f};

// sin/cos of m (radians) via 2-term Cody-Waite reduction into revolutions,
// then v_sin_f32/v_cos_f32. Error ~|m|*2^-48, far below f16 rounding.
__device__ inline void fsincos(float m, float& s, float& c) {
  constexpr double I2PI_D = 0.15915494309189533576888376337251;
  constexpr float HI = (float)I2PI_D;
  constexpr float LO = (float)(I2PI_D - (double)HI);
  float k = rintf(m * HI);
  float f = fmaf(m, HI, -k);
  f = fmaf(m, LO, f);
  s = __builtin_amdgcn_sinf(f);
  c = __builtin_amdgcn_cosf(f);
}

// fast silu: v_exp + v_rcp (~1ulp), avoids the precise-division sequence
__device__ inline float fsilu(float x) {
  return x * __builtin_amdgcn_rcpf(1.f + __expf(-x));
}

// ---------------- kernel 0: weight prep ----------------
// W1t/W2t: [n][k] f16. W3f: MFMA-fragment-major so layer3's weight loads are
// coalesced 16B/lane: (n,k) -> [((n>>4)*8 + (k>>5))*64 + ((k>>3)&3)*16 + (n&15)]*8 + (k&7)
__global__ __launch_bounds__(256) void prep_weights(
    const float* __restrict__ W1, const float* __restrict__ W2,
    const float* __restrict__ W3, _Float16* __restrict__ W1t,
    _Float16* __restrict__ W2t, _Float16* __restrict__ W3f) {
  int tid = blockIdx.x * blockDim.x + threadIdx.x;
  int stride = gridDim.x * blockDim.x;
  for (int i = tid; i < 128 * 32; i += stride) {
    int n = i >> 5, k = i & 31;
    W1t[i] = (_Float16)W1[k * 128 + n];
  }
  for (int i = tid; i < 256 * 128; i += stride) {
    int n = i >> 7, k = i & 127;
    W2t[i] = (_Float16)W2[k * 256 + n];
  }
  for (int i = tid; i < 512 * 256; i += stride) {  // coalesced read of W3
    int k = i >> 9, n = i & 511;
    int it = n >> 4, ln = n & 15, ks = k >> 5, q = (k >> 3) & 3, j = k & 7;
    W3f[((size_t)(it * 8 + ks) * 64 + q * 16 + ln) * 8 + j] = (_Float16)W3[i];
  }
}

// ---------------- kernel 1: feats + L1 + L2 + one-hot MFMA scatter ----------------
// 512 blocks = (bv[6]|tsel[1]|pg[2]), 512 threads, 256 pts as 2x128 chunks.
// One-hot scatter fragments built ONCE per chunk in LDS (8x dedup vs per-wave);
// two adjacent L2 C-tiles pack in-lane into one K=32 scatter B-frag (half the
// scatter MFMAs). h1 kept in fragment-major LDS: all accesses b64/b128,
// conflict-free. Silu/sincos via fast full-rate-trans sequences.
__global__ __launch_bounds__(512, 4) void embed_scatter(
    const float* __restrict__ dstart, const float* __restrict__ dend,
    const float* __restrict__ b1, const float* __restrict__ b2,
    const _Float16* __restrict__ W1t, const _Float16* __restrict__ W2t,
    _Float16* __restrict__ swz, int* __restrict__ counts) {
  __shared__ _Float16 h1f[16384];   // 32KB fragment-major h1
  __shared__ _Float16 W1lds[4096];  // 8KB
  __shared__ _Float16 ohs[8192];    // 16KB one-hot A-frags [(t*4+mc)*64+lane]*8
  __shared__ float b1lds[128];
  __shared__ unsigned char cellb[256];
  __shared__ int hist[64];

  int bid = blockIdx.x;
  int bv = bid >> 3, tsel = (bid >> 2) & 1, pg = bid & 3;
  const float* src = tsel ? dend : dstart;
  int tid = threadIdx.x;
  int lane = tid & 63, w = tid >> 6, ln = lane & 15, q = lane >> 4;

  *(half8*)&W1lds[tid * 8] = *(const half8*)&W1t[tid * 8];
  if (tid < 128) b1lds[tid] = b1[tid];
  if (tid < 64) hist[tid] = 0;
  __syncthreads();  // hist zero visible

  int pbase = bv * 1024 + pg * 256;
  if (tid < 256) {
    float2 xy = *(const float2*)&src[(size_t)(pbase + tid) * 2];
    int cell = ((int)xy.x >> 6) * 8 + ((int)xy.y >> 6);
    cellb[tid] = (unsigned char)cell;
    atomicAdd(&hist[cell], 1);
  }

  half8 w2f[2][4];  // B-frag of W2: n=32w+16nt+ln, k=32ks+8q+j
  float b2v[2];
  for (int nt = 0; nt < 2; nt++) {
    int n = w * 32 + nt * 16 + ln;
    b2v[nt] = b2[n];
    for (int ks = 0; ks < 4; ks++)
      w2f[nt][ks] = *(const half8*)&W2t[n * 128 + ks * 32 + q * 8];
  }
  floatx4 sacc[4][2];  // cell=16mc+4q+r, col=32w+16nt+ln
  for (int mc = 0; mc < 4; mc++)
    for (int nt = 0; nt < 2; nt++) sacc[mc][nt] = (floatx4){0.f, 0.f, 0.f, 0.f};

  float fA = FREQS[2 * q], fB = FREQS[2 * q + 1];
  __syncthreads();  // cellb ready

  for (int c = 0; c < 2; c++) {
    // --- phase A: build one-hot frags (2 entries/thread) + feats + L1 ---
    for (int e = 0; e < 2; e++) {
      int eid = tid * 2 + e;  // 0..1023 = (t[2]|mc[2]|lane[6])
      int l2 = eid & 63, mc = (eid >> 6) & 3, tt = eid >> 8;
      unsigned m = (unsigned)(mc * 16 + (l2 & 15));
      int pb = c * 128 + tt * 32 + (l2 >> 4) * 4;
      unsigned ca = *(const unsigned*)&cellb[pb];       // pts +0..3  (k j=0..3)
      unsigned cb = *(const unsigned*)&cellb[pb + 16];  // pts +16..19 (k j=4..7)
      unsigned d0 = ((ca & 255) == m ? 0x3C00u : 0u) | (((ca >> 8) & 255) == m ? 0x3C000000u : 0u);
      unsigned d1 = (((ca >> 16) & 255) == m ? 0x3C00u : 0u) | ((ca >> 24) == m ? 0x3C000000u : 0u);
      unsigned d2 = ((cb & 255) == m ? 0x3C00u : 0u) | (((cb >> 8) & 255) == m ? 0x3C000000u : 0u);
      unsigned d3 = (((cb >> 16) & 255) == m ? 0x3C00u : 0u) | ((cb >> 24) == m ? 0x3C000000u : 0u);
      uint4v u = {d0, d1, d2, d3};
      *(half8*)&ohs[eid * 8] = __builtin_bit_cast(half8, u);
    }
    // feats B-frag in regs: n=pt=ln, k=8q+j -> freqs 2q,2q+1
    int pl = c * 128 + w * 16 + ln;
    float2 xy = *(const float2*)&src[(size_t)(pbase + pl) * 2];
    half8 fb;
    {
      float s, cc2;
      fsincos(xy.x * fA, s, cc2); fb[0] = (_Float16)s; fb[2] = (_Float16)cc2;
      fsincos(xy.y * fA, s, cc2); fb[1] = (_Float16)s; fb[3] = (_Float16)cc2;
      fsincos(xy.x * fB, s, cc2); fb[4] = (_Float16)s; fb[6] = (_Float16)cc2;
      fsincos(xy.y * fB, s, cc2); fb[5] = (_Float16)s; fb[7] = (_Float16)cc2;
    }
    // L1 swapped (C[m=h1col][n=pt]) + silu -> fragment-major b64 write
    for (int mtW = 0; mtW < 8; mtW++) {
      half8 w1f = *(const half8*)&W1lds[(mtW * 16 + ln) * 32 + q * 8];
      floatx4 c1 = *(const floatx4*)&b1lds[mtW * 16 + q * 4];
      c1 = __builtin_amdgcn_mfma_f32_16x16x32_f16(w1f, fb, c1, 0, 0, 0);
      half4v hv;
      for (int r = 0; r < 4; r++) hv[r] = (_Float16)fsilu(c1[r]);
      int addr = (((w * 4 + (mtW >> 1)) * 4 + ((mtW & 1) * 2 + (q >> 1))) * 16 + ln) * 8 + (q & 1) * 4;
      *(half4v*)&h1f[addr] = hv;
    }
    __syncthreads();
    // --- phase B: L2 (pairs of 16-pt tiles) + K=32 one-hot scatter ---
    for (int t = 0; t < 4; t++) {
      half8 af0[4], af1[4];
      for (int ks = 0; ks < 4; ks++) {
        af0[ks] = *(const half8*)&h1f[((((2 * t) * 4 + ks) * 4 + q) * 16 + ln) * 8];
        af1[ks] = *(const half8*)&h1f[((((2 * t + 1) * 4 + ks) * 4 + q) * 16 + ln) * 8];
      }
      half8 oh[4];
      for (int mc = 0; mc < 4; mc++)
        oh[mc] = *(const half8*)&ohs[((t * 4 + mc) * 64 + lane) * 8];
      for (int nt = 0; nt < 2; nt++) {
        floatx4 c0 = {b2v[nt], b2v[nt], b2v[nt], b2v[nt]};
        floatx4 c1 = c0;
        for (int ks = 0; ks < 4; ks++) {
          c0 = __builtin_amdgcn_mfma_f32_16x16x32_f16(af0[ks], w2f[nt][ks], c0, 0, 0, 0);
          c1 = __builtin_amdgcn_mfma_f32_16x16x32_f16(af1[ks], w2f[nt][ks], c1, 0, 0, 0);
        }
        half8 hb;  // packed scatter B-frag: j=0..3 from even tile, 4..7 from odd
        for (int r = 0; r < 4; r++) {
          hb[r] = (_Float16)fsilu(c0[r]);
          hb[4 + r] = (_Float16)fsilu(c1[r]);
        }
        for (int mc = 0; mc < 4; mc++)
          sacc[mc][nt] = __builtin_amdgcn_mfma_f32_16x16x32_f16(oh[mc], hb, sacc[mc][nt], 0, 0, 0);
      }
    }
    __syncthreads();
  }
  // coalesced swizzled store: (bid, mc, wnt=2w+nt, lane) -> half4 (r0..r3)
  for (int mc = 0; mc < 4; mc++)
    for (int nt = 0; nt < 2; nt++) {
      half4v hv;
      for (int r = 0; r < 4; r++) hv[r] = (_Float16)sacc[mc][nt][r];
      *(half4v*)&swz[((((size_t)bid * 4 + mc) * 16 + w * 2 + nt) * 64 + lane) * 4] = hv;
    }
  if (tid < 64) counts[bid * 64 + tid] = hist[tid];
}

// ---------------- kernel 2: out = (Σ_pg partial) @ W3 + count*b3 ----------------
// 512 blocks = (bvts[128], outch-quarter[4]): 64 cells x 128 out-channels, full
// K=256. Unswizzle+pg-sum straight into B-frag-layout LDS; W3f loads coalesced.
__global__ __launch_bounds__(256) void layer3(
    const _Float16* __restrict__ swz, const int* __restrict__ counts,
    const _Float16* __restrict__ W3f, const float* __restrict__ b3,
    float* __restrict__ out) {
  __shared__ _Float16 bfrag[16384];  // 32KB: [((cn*8+ks)*4+q)*16+ln2]*8+j, k=32ks+8q+j
  __shared__ float cnt_s[64];
  int bvts = blockIdx.x;  // 0..127
  int ch2 = blockIdx.y;   // 0..3 (128-outch quarter)
  int tid = threadIdx.x;
  // stage: swz entry (mc, wnt, l, r) holds h2[cell=mc*16+4(l>>4)+r][col=wnt*16+(l&15)]
  for (int it = 0; it < 16; it++) {
    int idx = it * 256 + tid;  // (mc[2]|wnt[4]|l[6])
    int mc = idx >> 10, wnt = (idx >> 6) & 15, l = idx & 63;
    int qq = l >> 4, lnn = l & 15;
    size_t base = (size_t)bvts * 16384 + (size_t)idx;  // in half4 units (pg=0)
    half4v s = (*(const half4v*)&swz[base * 4] +
                *(const half4v*)&swz[(base + 4096) * 4]) +
               (*(const half4v*)&swz[(base + 8192) * 4] +
                *(const half4v*)&swz[(base + 12288) * 4]);
    int abase = ((mc * 8 + (wnt >> 1)) * 4 + ((wnt & 1) * 2 + (lnn >> 3))) * 16;
    for (int r = 0; r < 4; r++)
      bfrag[(abase + qq * 4 + r) * 8 + (lnn & 7)] = s[r];
  }
  if (tid < 64) {
    int base = bvts * 256 + tid;
    cnt_s[tid] = (float)(counts[base] + counts[base + 64] +
                         counts[base + 128] + counts[base + 192]);
  }
  __syncthreads();
  int lane = tid & 63, w = tid >> 6, ln = lane & 15, q = lane >> 4;
  floatx4 acc[2][4];
  for (int i2 = 0; i2 < 2; i2++)
    for (int cn = 0; cn < 4; cn++) acc[i2][cn] = (floatx4){0.f, 0.f, 0.f, 0.f};
  for (int ks = 0; ks < 8; ks++) {
    half8 bf[4];
    for (int cn = 0; cn < 4; cn++)
      bf[cn] = *(const half8*)&bfrag[(((cn * 8 + ks) * 4 + q) * 16 + ln) * 8];
    for (int i2 = 0; i2 < 2; i2++) {
      int I = ch2 * 8 + w * 2 + i2;  // global 16-outch tile
      half8 wf = *(const half8*)&W3f[(size_t)((I * 8 + ks) * 64 + lane) * 8];
      for (int cn = 0; cn < 4; cn++)
        acc[i2][cn] = __builtin_amdgcn_mfma_f32_16x16x32_f16(wf, bf[cn], acc[i2][cn], 0, 0, 0);
    }
  }
  for (int i2 = 0; i2 < 2; i2++) {
    int nb = ch2 * 128 + (w * 2 + i2) * 16;
    floatx4 b3v = *(const floatx4*)&b3[nb + q * 4];
    for (int cn = 0; cn < 4; cn++) {
      float cf = cnt_s[cn * 16 + ln];
      for (int r = 0; r < 4; r++)
        out[((size_t)bvts * 512 + nb + q * 4 + r) * 64 + cn * 16 + ln] =
            acc[i2][cn][r] + cf * b3v[r];
    }
  }
}

extern "C" void kernel_launch(void* const* d_in, const int* in_sizes, int n_in,
                              void* d_out, int out_size, void* d_ws, size_t ws_size,
                              hipStream_t stream) {
  const float* dstart = (const float*)d_in[0];
  const float* dend = (const float*)d_in[1];
  const float* W1 = (const float*)d_in[2];
  const float* b1 = (const float*)d_in[3];
  const float* W2 = (const float*)d_in[4];
  const float* b2 = (const float*)d_in[5];
  const float* W3 = (const float*)d_in[6];
  const float* b3 = (const float*)d_in[7];
  float* out = (float*)d_out;

  char* ws = (char*)d_ws;
  _Float16* W1t = (_Float16*)(ws);               // 8 KB
  _Float16* W2t = (_Float16*)(ws + 8192);        // 64 KB
  _Float16* W3f = (_Float16*)(ws + 73728);       // 256 KB
  _Float16* swz = (_Float16*)(ws + 335872);      // 512*64*256*2 = 16 MB
  int* counts = (int*)(ws + 335872 + 16777216);  // 128 KB

  hipLaunchKernelGGL(prep_weights, dim3(64), dim3(256), 0, stream,
                     W1, W2, W3, W1t, W2t, W3f);
  hipLaunchKernelGGL(embed_scatter, dim3(512), dim3(512), 0, stream,
                     dstart, dend, b1, b2, W1t, W2t, swz, counts);
  hipLaunchKernelGGL(layer3, dim3(128, 4), dim3(256), 0, stream,
                     swz, counts, W3f, b3, out);
}

// Round 5
// 120.088 us; speedup vs baseline: 1.0693x; 1.0693x over previous
//
#include <hip/hip_runtime.h>
#include <hip/hip_bf16.h>

typedef _Float16 half8 __attribute__((ext_vector_type(8)));
typedef _Float16 half4v __attribute__((ext_vector_type(4)));
typedef float floatx4 __attribute__((ext_vector_type(4)));
typedef unsigned int uint2v __attribute__((ext_vector_type(2)));

// 100^(i/8), i=0..7, correctly rounded
__device__ const float FREQS[8] = {
    1.0f, 1.7782794100389228f, 3.1622776601683795f, 5.623413251903491f,
    10.0f, 17.78279410038923f, 31.622776601683793f, 56.23413251903491f};

// sin/cos of m (radians) via 2-term Cody-Waite reduction into revolutions,
// then v_sin_f32/v_cos_f32. Error ~|m|*2^-48, far below f16 rounding.
__device__ inline void fsincos(float m, float& s, float& c) {
  constexpr double I2PI_D = 0.15915494309189533576888376337251;
  constexpr float HI = (float)I2PI_D;
  constexpr float LO = (float)(I2PI_D - (double)HI);
  float k = rintf(m * HI);
  float f = fmaf(m, HI, -k);
  f = fmaf(m, LO, f);
  s = __builtin_amdgcn_sinf(f);
  c = __builtin_amdgcn_cosf(f);
}

// fast silu: v_exp + v_rcp (~1ulp), avoids the precise-division sequence
__device__ inline float fsilu(float x) {
  return x * __builtin_amdgcn_rcpf(1.f + __expf(-x));
}

// ---------------- kernel 0: W3 -> MFMA-fragment-major f16, coalesced stores ----
// frag id t = (I*8+ks)*64 + q*16 + ln holds W3[k=32ks+8q+j][n=16I+ln], j=0..7
__global__ __launch_bounds__(256) void prep_w3(const float* __restrict__ W3,
                                               _Float16* __restrict__ W3f) {
  int t = blockIdx.x * 256 + threadIdx.x;  // 16384 frags
  int ln = t & 15, q = (t >> 4) & 3, ks = (t >> 6) & 7, I = t >> 9;
  half8 v;
  for (int j = 0; j < 8; j++)
    v[j] = (_Float16)W3[(size_t)(ks * 32 + q * 8 + j) * 512 + I * 16 + ln];
  *(half8*)&W3f[(size_t)t * 8] = v;
}

// ---------------- kernel 1: feats + L1 + L2 + one-hot MFMA scatter ----------------
// 512 blocks = (bv[6]|tsel[1]|pg[2]), 512 threads, 256 pts as 2x128 chunks.
// One-hot built IN REGISTERS (VALU has headroom; LDS is the bottleneck pipe).
// h1 fragment-major in LDS (b64 writes / b128 reads, conflict-free). Tail
// transposes sacc through LDS so swz is written in layer3's B-frag layout
// with coalesced b128 stores. W1/W2 converted from f32 in-kernel (prep-free).
__global__ __launch_bounds__(512, 4) void embed_scatter(
    const float* __restrict__ dstart, const float* __restrict__ dend,
    const float* __restrict__ W1, const float* __restrict__ b1,
    const float* __restrict__ W2, const float* __restrict__ b2,
    _Float16* __restrict__ swz, int* __restrict__ counts) {
  __shared__ _Float16 smem[16384 + 4096];  // h1f (32KB) | W1lds (8KB)
  _Float16* h1f = smem;
  _Float16* W1lds = smem + 16384;
  _Float16* h2t = smem;  // tail overlay: 64*264=16896 halves <= 20480
  __shared__ float b1lds[128];
  __shared__ unsigned char cellb[256];
  __shared__ int hist[64];

  int bid = blockIdx.x;
  int bv = bid >> 3, tsel = (bid >> 2) & 1, pg = bid & 3;
  const float* src = tsel ? dend : dstart;
  int tid = threadIdx.x;
  int lane = tid & 63, w = tid >> 6, ln = lane & 15, q = lane >> 4;

  {  // W1lds[n*32+k] = W1[k*128+n]
    int n = tid >> 2, kb = (tid & 3) * 8;
    half8 v;
    for (int j = 0; j < 8; j++) v[j] = (_Float16)W1[(kb + j) * 128 + n];
    *(half8*)&W1lds[n * 32 + kb] = v;
  }
  if (tid < 128) b1lds[tid] = b1[tid];
  if (tid < 64) hist[tid] = 0;
  __syncthreads();  // hist zero + W1lds visible

  int pbase = bv * 1024 + pg * 256;
  if (tid < 256) {
    float2 xy = *(const float2*)&src[(size_t)(pbase + tid) * 2];
    int cell = ((int)xy.x >> 6) * 8 + ((int)xy.y >> 6);
    cellb[tid] = (unsigned char)cell;
    atomicAdd(&hist[cell], 1);
  }

  // W2 B-frags direct from f32: n=32w+16nt+ln, k=32ks+8q+j (L2/L3-hot)
  half8 w2f[2][4];
  float b2v[2];
  for (int nt = 0; nt < 2; nt++) {
    int n = w * 32 + nt * 16 + ln;
    b2v[nt] = b2[n];
    for (int ks = 0; ks < 4; ks++) {
      half8 v;
      for (int j = 0; j < 8; j++)
        v[j] = (_Float16)W2[(ks * 32 + q * 8 + j) * 256 + n];
      w2f[nt][ks] = v;
    }
  }
  floatx4 sacc[4][2];  // cell=16mc+4q+r, col=32w+16nt+ln
  for (int mc = 0; mc < 4; mc++)
    for (int nt = 0; nt < 2; nt++) sacc[mc][nt] = (floatx4){0.f, 0.f, 0.f, 0.f};

  float fA = FREQS[2 * q], fB = FREQS[2 * q + 1];
  __syncthreads();  // cellb ready

  for (int c = 0; c < 2; c++) {
    // --- phase A: feats (regs) + L1 -> fragment-major h1 LDS ---
    int pl = c * 128 + w * 16 + ln;
    float2 xy = *(const float2*)&src[(size_t)(pbase + pl) * 2];
    half8 fb;  // feats B-frag: n=pt=ln, k=8q+j -> freqs 2q,2q+1
    {
      float s, cc2;
      fsincos(xy.x * fA, s, cc2); fb[0] = (_Float16)s; fb[2] = (_Float16)cc2;
      fsincos(xy.y * fA, s, cc2); fb[1] = (_Float16)s; fb[3] = (_Float16)cc2;
      fsincos(xy.x * fB, s, cc2); fb[4] = (_Float16)s; fb[6] = (_Float16)cc2;
      fsincos(xy.y * fB, s, cc2); fb[5] = (_Float16)s; fb[7] = (_Float16)cc2;
    }
    for (int mtW = 0; mtW < 8; mtW++) {
      half8 w1f = *(const half8*)&W1lds[(mtW * 16 + ln) * 32 + q * 8];
      floatx4 c1 = *(const floatx4*)&b1lds[mtW * 16 + q * 4];
      c1 = __builtin_amdgcn_mfma_f32_16x16x32_f16(w1f, fb, c1, 0, 0, 0);
      half4v hv;
      for (int r = 0; r < 4; r++) hv[r] = (_Float16)fsilu(c1[r]);
      int addr = (((w * 4 + (mtW >> 1)) * 4 + ((mtW & 1) * 2 + (q >> 1))) * 16 + ln) * 8 + (q & 1) * 4;
      *(half4v*)&h1f[addr] = hv;
    }
    __syncthreads();
    // --- phase B: L2 + register one-hot scatter (K=16) ---
    for (int tt = 0; tt < 8; tt++) {
      half8 af[4];
      for (int ks = 0; ks < 4; ks++)
        af[ks] = *(const half8*)&h1f[(((tt * 4 + ks) * 4 + q) * 16 + ln) * 8];
      unsigned ca = *(const unsigned*)&cellb[c * 128 + tt * 16 + q * 4];
      unsigned e0 = ca & 255, e1 = (ca >> 8) & 255, e2 = (ca >> 16) & 255, e3 = ca >> 24;
      half4v oh[4];  // one-hot A: m=16mc+ln (cell), k=4q+j (pt tt*16+4q+j)
      for (int mc = 0; mc < 4; mc++) {
        unsigned m = (unsigned)(mc * 16 + ln);
        unsigned d0 = (e0 == m ? 0x3C00u : 0u) | (e1 == m ? 0x3C000000u : 0u);
        unsigned d1 = (e2 == m ? 0x3C00u : 0u) | (e3 == m ? 0x3C000000u : 0u);
        uint2v u = {d0, d1};
        oh[mc] = __builtin_bit_cast(half4v, u);
      }
      for (int nt = 0; nt < 2; nt++) {
        floatx4 cc = {b2v[nt], b2v[nt], b2v[nt], b2v[nt]};
        for (int ks = 0; ks < 4; ks++)
          cc = __builtin_amdgcn_mfma_f32_16x16x32_f16(af[ks], w2f[nt][ks], cc, 0, 0, 0);
        half4v hb;  // L2 C-layout == scatter B-layout (k=pt=4q+r, n=col=ln)
        for (int r = 0; r < 4; r++) hb[r] = (_Float16)fsilu(cc[r]);
        for (int mc = 0; mc < 4; mc++)
          sacc[mc][nt] = __builtin_amdgcn_mfma_f32_16x16x16f16(oh[mc], hb, sacc[mc][nt], 0, 0, 0);
      }
    }
    __syncthreads();
  }

  // --- tail: transpose sacc -> B-frag-layout swz via LDS (h2t overlays h1f) ---
  for (int mc = 0; mc < 4; mc++)
    for (int nt = 0; nt < 2; nt++)
      for (int r = 0; r < 4; r++)
        h2t[(mc * 16 + q * 4 + r) * 264 + w * 32 + nt * 16 + ln] =
            (_Float16)sacc[mc][nt][r];
  __syncthreads();
  for (int i = 0; i < 4; i++) {
    int g = i * 512 + tid;  // frag id: (cn[2]|ks[3]|qq[2]|lnn[4])
    int lnn = g & 15, qq = (g >> 4) & 3, ks2 = (g >> 6) & 7, cn = g >> 9;
    half8 v = *(const half8*)&h2t[(cn * 16 + lnn) * 264 + ks2 * 32 + qq * 8];
    *(half8*)&swz[(size_t)bid * 16384 + (size_t)g * 8] = v;  // coalesced b128
  }
  if (tid < 64) counts[bid * 64 + tid] = hist[tid];
}

// ---------------- kernel 2: out = (Σ_pg h2sum) @ W3 + count*b3 ----------------
// 512 blocks = (bvts[128] x outch-quarter[4]). swz is already B-frag-major:
// stage = coalesced b128 loads of 4 pg + pk-add + identity b128 LDS write.
__global__ __launch_bounds__(256) void layer3(
    const _Float16* __restrict__ swz, const int* __restrict__ counts,
    const _Float16* __restrict__ W3f, const float* __restrict__ b3,
    float* __restrict__ out) {
  __shared__ _Float16 blds[16384];  // 32KB, frag-major (same layout as swz)
  __shared__ float cnt_s[64];
  int bvts = blockIdx.x;  // 0..127
  int ch2 = blockIdx.y;   // 0..3 (128-outch quarter)
  int tid = threadIdx.x;
  const _Float16* sb = swz + (size_t)bvts * 65536;  // 4 pg x 16384
  for (int i = 0; i < 8; i++) {
    int g = i * 256 + tid;
    half8 v0 = *(const half8*)&sb[(size_t)g * 8];
    half8 v1 = *(const half8*)&sb[16384 + (size_t)g * 8];
    half8 v2 = *(const half8*)&sb[32768 + (size_t)g * 8];
    half8 v3 = *(const half8*)&sb[49152 + (size_t)g * 8];
    *(half8*)&blds[g * 8] = (v0 + v1) + (v2 + v3);
  }
  if (tid < 64) {
    int base = bvts * 256 + tid;
    cnt_s[tid] = (float)(counts[base] + counts[base + 64] +
                         counts[base + 128] + counts[base + 192]);
  }
  __syncthreads();
  int lane = tid & 63, w = tid >> 6, ln = lane & 15, q = lane >> 4;
  floatx4 acc[2][4];
  for (int i2 = 0; i2 < 2; i2++)
    for (int cn = 0; cn < 4; cn++) acc[i2][cn] = (floatx4){0.f, 0.f, 0.f, 0.f};
  for (int ks = 0; ks < 8; ks++) {
    half8 bf[4];  // B[k=32ks+8q+j][n=cell 16cn+ln]
    for (int cn = 0; cn < 4; cn++)
      bf[cn] = *(const half8*)&blds[(((cn * 8 + ks) * 4 + q) * 16 + ln) * 8];
    for (int i2 = 0; i2 < 2; i2++) {
      int I = ch2 * 8 + w * 2 + i2;  // 16-outch tile
      half8 wf = *(const half8*)&W3f[(size_t)((I * 8 + ks) * 64 + lane) * 8];
      for (int cn = 0; cn < 4; cn++)
        acc[i2][cn] = __builtin_amdgcn_mfma_f32_16x16x32_f16(wf, bf[cn], acc[i2][cn], 0, 0, 0);
    }
  }
  for (int i2 = 0; i2 < 2; i2++) {
    int nb = ch2 * 128 + (w * 2 + i2) * 16;
    floatx4 b3v = *(const floatx4*)&b3[nb + q * 4];
    for (int cn = 0; cn < 4; cn++) {
      float cf = cnt_s[cn * 16 + ln];
      for (int r = 0; r < 4; r++)
        out[((size_t)bvts * 512 + nb + q * 4 + r) * 64 + cn * 16 + ln] =
            acc[i2][cn][r] + cf * b3v[r];
    }
  }
}

extern "C" void kernel_launch(void* const* d_in, const int* in_sizes, int n_in,
                              void* d_out, int out_size, void* d_ws, size_t ws_size,
                              hipStream_t stream) {
  const float* dstart = (const float*)d_in[0];
  const float* dend = (const float*)d_in[1];
  const float* W1 = (const float*)d_in[2];
  const float* b1 = (const float*)d_in[3];
  const float* W2 = (const float*)d_in[4];
  const float* b2 = (const float*)d_in[5];
  const float* W3 = (const float*)d_in[6];
  const float* b3 = (const float*)d_in[7];
  float* out = (float*)d_out;

  char* ws = (char*)d_ws;
  _Float16* W3f = (_Float16*)(ws);               // 256 KB
  _Float16* swz = (_Float16*)(ws + 262144);      // 512*16384*2 = 16 MB
  int* counts = (int*)(ws + 262144 + 16777216);  // 128 KB

  hipLaunchKernelGGL(prep_w3, dim3(64), dim3(256), 0, stream, W3, W3f);
  hipLaunchKernelGGL(embed_scatter, dim3(512), dim3(512), 0, stream,
                     dstart, dend, W1, b1, W2, b2, swz, counts);
  hipLaunchKernelGGL(layer3, dim3(128, 4), dim3(256), 0, stream,
                     swz, counts, W3f, b3, out);
}